// Round 7
// baseline (234.807 us; speedup 1.0000x reference)
//
#include <hip/hip_runtime.h>
#include <math.h>

#define NB 4096
#define NN 10000
#define ND 256
#define ND4 64                 // float4 per row
#define ALPHA 0.2f
#define CS 16                  // rows per chunk
#define NG 625                 // chunks (exact: 625*16 = 10000)
#define SCHUNK 25              // chunks per superchunk
#define NSUPER 25              // superchunks
#define NBLK 512               // persistent grid: 2 blocks/CU guaranteed resident
#define NTHR 256
#define NWAVE (NBLK * 4)       // 2048 waves
#define RCHUNKS 157            // ceil(NN/64) n-chunks for rank phase
#define RSEGS 13               // m-segments; 157*13 = 2041 <= 2048 wave-units
#define RSEGLEN 770            // ceil(NN/13)
#define NBAR 4
#define ZELEMS (NN + 2 * NSUPER * ND + 2 * NSUPER)   // rank+SSA+SSC+ssa0+ssc0

typedef unsigned long long u64;

// One-shot global barrier. Arrival slots are write-before-read (initial
// poison/garbage reads as "not arrived" — no init needed). Block 0 aggregates
// 512 slots with __syncthreads_count, releases flag; others poll relaxed and
// acquire once at exit. Release on the arrival store publishes each block's
// phase writes; the final fence invalidates stale L1/L2 for the next phase.
__device__ __forceinline__ void gbar(int phase, unsigned* __restrict__ arrive,
                                     unsigned* __restrict__ flag) {
  const unsigned VAL = 0x51B00000u + (unsigned)phase;
  __syncthreads();
  if (threadIdx.x == 0)
    __hip_atomic_store(&arrive[phase * NBLK + (int)blockIdx.x], VAL,
                       __ATOMIC_RELEASE, __HIP_MEMORY_SCOPE_AGENT);
  if (blockIdx.x == 0) {
    for (;;) {
      unsigned a = __hip_atomic_load(&arrive[phase * NBLK + (int)threadIdx.x],
                                     __ATOMIC_RELAXED, __HIP_MEMORY_SCOPE_AGENT);
      unsigned b = __hip_atomic_load(&arrive[phase * NBLK + NTHR + (int)threadIdx.x],
                                     __ATOMIC_RELAXED, __HIP_MEMORY_SCOPE_AGENT);
      int bad = (a != VAL) || (b != VAL);
      if (__syncthreads_count(bad) == 0) break;
      __builtin_amdgcn_s_sleep(1);
    }
    if (threadIdx.x == 0)
      __hip_atomic_store(&flag[phase], VAL, __ATOMIC_RELEASE,
                         __HIP_MEMORY_SCOPE_AGENT);
  } else if (threadIdx.x == 0) {
    while (__hip_atomic_load(&flag[phase], __ATOMIC_RELAXED,
                             __HIP_MEMORY_SCOPE_AGENT) != VAL)
      __builtin_amdgcn_s_sleep(1);
  }
  __syncthreads();
  __builtin_amdgcn_fence(__ATOMIC_ACQUIRE, "agent");
}

__global__ __launch_bounds__(NTHR) void k_all(
    const float* __restrict__ P, const float* __restrict__ V,
    const float* __restrict__ K, float* __restrict__ out,
    char* __restrict__ ws) {
  // ---- workspace layout ----
  u64* tk = (u64*)ws;                              // NN sortable keys
  unsigned* arrive = (unsigned*)(tk + NN);         // NBAR*NBLK barrier slots
  unsigned* flag = arrive + NBAR * NBLK;           // NBAR flags (+4 pad)
  int* rank = (int*)(flag + NBAR + 4);             // --- zero region start ---
  float* SSA = (float*)(rank + NN);
  float* SSC = SSA + NSUPER * ND;
  float* ssa0 = SSC + NSUPER * ND;
  float* ssc0 = ssa0 + NSUPER;                     // --- zero region end ---
  float* t = ssc0 + NSUPER;
  float* s = t + NN;
  float* tsort = s + NB;
  float* eA = tsort + NN;
  float* eC = eA + NN;
  int* idxs = (int*)(eC + NN);
  int* kk = idxs + NN;
  float* SA = (float*)(kk + NB);
  float* SC = SA + NG * ND;
  float* sa0 = SC + NG * ND;
  float* sc0 = sa0 + NG;

  const int tid = threadIdx.x;
  const int bid = blockIdx.x;
  const int gt = bid * NTHR + tid;
  const int w = gt >> 6;          // global wave id (0..NWAVE-1)
  const int lane = tid & 63;

  // ---- Phase A: zero accumulators; dots + sortable keys ----
  if (gt < ZELEMS) rank[gt] = 0;  // covers rank,SSA,SSC,ssa0,ssc0 (contiguous)
  for (int j = w; j < NN + NB; j += NWAVE) {
    bool isn = (j < NN);
    const float* row = isn ? V + (size_t)j * ND : P + (size_t)(j - NN) * ND;
    const float* wv = isn ? K + ND : K;
    float4 r = ((const float4*)row)[lane];
    float4 kx = ((const float4*)wv)[lane];
    float acc = r.x * kx.x + r.y * kx.y + r.z * kx.z + r.w * kx.w;
    #pragma unroll
    for (int off = 32; off; off >>= 1) acc += __shfl_down(acc, off, 64);
    if (lane == 0) {
      if (isn) {
        t[j] = acc;
        unsigned bits = __float_as_uint(acc);
        unsigned key = bits ^ (((int)bits >> 31) | 0x80000000u);  // monotone
        tk[j] = ((u64)key << 14) | (unsigned)j;                   // strict order
      } else {
        s[j - NN] = acc;
      }
    }
  }
  gbar(0, arrive, flag);

  // ---- Phase B: partial ranks. wave-unit = (n-chunk of 64, m-segment) ----
  if (w < RCHUNKS * RSEGS) {
    int c = w % RCHUNKS, seg = w / RCHUNKS;
    int n = (c << 6) + lane;
    u64 kn = (n < NN) ? tk[n] : ~0ull;
    int m0 = __builtin_amdgcn_readfirstlane(seg * RSEGLEN);
    int m1 = min(NN, m0 + RSEGLEN);
    int r = 0, m = m0;
    #pragma unroll 1
    for (; m + 4 <= m1; m += 4) {
      u64 a = tk[m], b2 = tk[m + 1], c2 = tk[m + 2], d2 = tk[m + 3];
      r += (int)(a < kn) + (int)(b2 < kn) + (int)(c2 < kn) + (int)(d2 < kn);
    }
    for (; m < m1; ++m) r += (int)(tk[m] < kn);
    if (n < NN && r) atomicAdd(&rank[n], r);
  }
  gbar(1, arrive, flag);

  // ---- Phase C: scatter into sorted order + exp factors ----
  for (int n = gt; n < NN; n += NBLK * NTHR) {
    int r = rank[n];
    float tn = t[n];
    tsort[r] = tn;
    eA[r] = __expf(tn);
    eC[r] = __expf(ALPHA * tn);
    idxs[r] = n;
  }
  gbar(2, arrive, flag);

  // ---- Phase D: chunk sums (waves 0..624) + binary searches (top 16 blocks) ----
  if (w < NG) {
    int g = w;
    const float4* V4 = (const float4*)V;
    float4 aA = {0.f, 0.f, 0.f, 0.f}, aC = {0.f, 0.f, 0.f, 0.f};
    float sa = 0.f, sc = 0.f;
    int base = g * CS;
    #pragma unroll
    for (int j = 0; j < CS; ++j) {
      int i = base + j;
      float ea = eA[i], ec = eC[i];   // wave-uniform
      int id = idxs[i];
      float4 v = V4[(size_t)id * ND4 + lane];
      aA.x += ea * v.x; aA.y += ea * v.y; aA.z += ea * v.z; aA.w += ea * v.w;
      aC.x += ec * v.x; aC.y += ec * v.y; aC.z += ec * v.z; aC.w += ec * v.w;
      sa += ea; sc += ec;
    }
    ((float4*)SA)[(size_t)g * ND4 + lane] = aA;
    ((float4*)SC)[(size_t)g * ND4 + lane] = aC;
    int gs = g / SCHUNK;
    float* pA = &SSA[(size_t)gs * ND + lane * 4];
    float* pC = &SSC[(size_t)gs * ND + lane * 4];
    atomicAdd(pA + 0, aA.x); atomicAdd(pA + 1, aA.y);
    atomicAdd(pA + 2, aA.z); atomicAdd(pA + 3, aA.w);
    atomicAdd(pC + 0, aC.x); atomicAdd(pC + 1, aC.y);
    atomicAdd(pC + 2, aC.z); atomicAdd(pC + 3, aC.w);
    if (lane == 0) {
      sa0[g] = sa; sc0[g] = sc;
      atomicAdd(&ssa0[gs], sa);
      atomicAdd(&ssc0[gs], sc);
    }
  }
  if (bid >= NBLK - 16) {
    int b = (bid - (NBLK - 16)) * NTHR + tid;    // 16*256 = 4096 = NB
    float key = -s[b];
    int lo = 0, hi = NN;   // lower_bound: first idx with tsort[idx] >= key
    while (lo < hi) {
      int mid = (lo + hi) >> 1;
      if (tsort[mid] < key) lo = mid + 1; else hi = mid;
    }
    kk[b] = lo;
  }
  gbar(3, arrive, flag);

  // ---- Phase E: finalize, one wave per patient ----
  const float4* SSA4 = (const float4*)SSA;
  const float4* SSC4 = (const float4*)SSC;
  const float4* SA4 = (const float4*)SA;
  const float4* SC4 = (const float4*)SC;
  const float4* V4 = (const float4*)V;
  for (int b = w; b < NB; b += NWAVE) {
    int k = kk[b];
    int g = k >> 4;         // chunk idx; k==NN -> g==NG
    int gs = g / SCHUNK;    // superchunk idx; g==NG -> gs==NSUPER
    float4 sA = {0.f, 0.f, 0.f, 0.f}, pC = {0.f, 0.f, 0.f, 0.f};
    float suffa = 0.f, prefc = 0.f;
    for (int q = gs; q < NSUPER; ++q) {
      float4 v = SSA4[(size_t)q * ND4 + lane];
      sA.x += v.x; sA.y += v.y; sA.z += v.z; sA.w += v.w;
      suffa += ssa0[q];
    }
    for (int q = 0; q < gs; ++q) {
      float4 v = SSC4[(size_t)q * ND4 + lane];
      pC.x += v.x; pC.y += v.y; pC.z += v.z; pC.w += v.w;
      prefc += ssc0[q];
    }
    for (int j = gs * SCHUNK; j < g; ++j) {
      float4 a = SA4[(size_t)j * ND4 + lane];
      float4 c = SC4[(size_t)j * ND4 + lane];
      sA.x -= a.x; sA.y -= a.y; sA.z -= a.z; sA.w -= a.w;
      pC.x += c.x; pC.y += c.y; pC.z += c.z; pC.w += c.w;
      suffa -= sa0[j]; prefc += sc0[j];
    }
    for (int i = g << 4; i < k; ++i) {
      float ea = eA[i], ec = eC[i];
      float4 v = V4[(size_t)idxs[i] * ND4 + lane];
      sA.x -= ea * v.x; sA.y -= ea * v.y; sA.z -= ea * v.z; sA.w -= ea * v.w;
      pC.x += ec * v.x; pC.y += ec * v.y; pC.z += ec * v.z; pC.w += ec * v.w;
      suffa -= ea; prefc += ec;
    }
    float sb = s[b];
    float ea = __expf(sb), ec = __expf(ALPHA * sb);
    float inv = 1.f / (ea * suffa + ec * prefc);
    float4 p = ((const float4*)P)[(size_t)b * ND4 + lane];
    float4 o;
    o.x = p.x + (ea * sA.x + ec * pC.x) * inv;
    o.y = p.y + (ea * sA.y + ec * pC.y) * inv;
    o.z = p.z + (ea * sA.z + ec * pC.z) * inv;
    o.w = p.w + (ea * sA.w + ec * pC.w) * inv;
    ((float4*)out)[(size_t)b * ND4 + lane] = o;
  }
}

extern "C" void kernel_launch(void* const* d_in, const int* in_sizes, int n_in,
                              void* d_out, int out_size, void* d_ws, size_t ws_size,
                              hipStream_t stream) {
  const float* P = (const float*)d_in[0];   // (B, D)
  const float* V = (const float*)d_in[1];   // (N, D)
  const float* K = (const float*)d_in[2];   // (2D, 1)
  float* out = (float*)d_out;
  char* ws = (char*)d_ws;

  k_all<<<NBLK, NTHR, 0, stream>>>(P, V, K, out, ws);
}

// Round 8
// 145.687 us; speedup vs baseline: 1.6117x; 1.6117x over previous
//
#include <hip/hip_runtime.h>
#include <math.h>

#define NB 4096
#define NN 10000
#define ND 256
#define ALPHA 0.2f
#define CS 16                 // rows per chunk
#define NG (NN / CS)          // 625 chunks (exact)
#define SCHUNK 25             // chunks per superchunk
#define NSUPER (NG / SCHUNK)  // 25 superchunks (exact)
#define NTILES 40             // 40*256 >= 10000
#define MSEGS 26
#define SEGLEN ((NN + MSEGS - 1) / MSEGS)   // 385
#define FPB 8                 // patients per finalize block
// zero region: rank[NN] + ntdone[NTILES] + SSA/SSC + ssa0/ssc0
#define ZELEMS (NN + NTILES + 2 * NSUPER * ND + 2 * NSUPER)

typedef unsigned long long u64;

// --- 1) dots t_n=V[n]·Wn, s_b=P[b]·Wp (one wave/row); strict-total-order u64
// keys tk[n]; zero the atomic-accumulator region.
__global__ __launch_bounds__(256) void k_dot(
    const float* __restrict__ P, const float* __restrict__ V,
    const float* __restrict__ K,
    float* __restrict__ t, float* __restrict__ s, u64* __restrict__ tk,
    int* __restrict__ zero_region) {
  int gt = blockIdx.x * 256 + threadIdx.x;
  if (gt < ZELEMS) zero_region[gt] = 0;
  int j = blockIdx.x * 4 + (threadIdx.x >> 6);
  int lane = threadIdx.x & 63;
  if (j >= NN + NB) return;
  const float* row; const float* wv; int oi; bool isn;
  if (j < NN) { row = V + (size_t)j * ND; wv = K + ND; oi = j; isn = true; }
  else        { row = P + (size_t)(j - NN) * ND; wv = K; oi = j - NN; isn = false; }
  float4 r  = ((const float4*)row)[lane];
  float4 kx = ((const float4*)wv)[lane];
  float acc = r.x * kx.x + r.y * kx.y + r.z * kx.z + r.w * kx.w;
  #pragma unroll
  for (int off = 32; off; off >>= 1) acc += __shfl_down(acc, off, 64);
  if (lane == 0) {
    if (isn) {
      t[oi] = acc;
      unsigned bits = __float_as_uint(acc);
      unsigned key = bits ^ (((int)bits >> 31) | 0x80000000u);  // monotone map
      tk[oi] = ((u64)key << 14) | (unsigned)oi;
    } else {
      s[oi] = acc;
    }
  }
}

// --- 2) rank + winner-block scatter. Grid (NTILES, MSEGS).
// Partial ranks via wave-uniform key loads -> atomicAdd. Then ACQ_REL inc of
// ntdone[ntile]; the 26th arriver issues ONE agent acquire fence (invalidates
// stale L1/L2) and scatters with plain coalesced loads of the final ranks.
__global__ __launch_bounds__(256) void k_rank_scatter(
    const u64* __restrict__ tk, const float* __restrict__ t,
    int* __restrict__ rank, int* __restrict__ ntdone,
    float* __restrict__ tsort, float* __restrict__ eA, float* __restrict__ eC,
    int* __restrict__ idxs) {
  int ntile = blockIdx.x, seg = blockIdx.y;
  int n = ntile * 256 + threadIdx.x;
  u64 kn = (n < NN) ? tk[n] : ~0ull;
  int m0 = seg * SEGLEN, m1 = min(NN, m0 + SEGLEN);
  int r = 0;
  int m = m0;
  #pragma unroll 1
  for (; m + 4 <= m1; m += 4) {
    u64 a = tk[m], b2 = tk[m + 1], c2 = tk[m + 2], d2 = tk[m + 3];
    r += (int)(a < kn) + (int)(b2 < kn) + (int)(c2 < kn) + (int)(d2 < kn);
  }
  for (; m < m1; ++m) r += (int)(tk[m] < kn);
  if (n < NN && r) atomicAdd(&rank[n], r);
  __syncthreads();
  __shared__ int who;
  if (threadIdx.x == 0)
    who = __hip_atomic_fetch_add(&ntdone[ntile], 1, __ATOMIC_ACQ_REL,
                                 __HIP_MEMORY_SCOPE_AGENT);
  __syncthreads();
  if (who == MSEGS - 1) {
    __builtin_amdgcn_fence(__ATOMIC_ACQUIRE, "agent");  // one fence, then plain loads
    if (n < NN) {
      int rr = rank[n];
      float tn = t[n];
      tsort[rr] = tn;
      eA[rr] = __expf(tn);
      eC[rr] = __expf(ALPHA * tn);
      idxs[rr] = n;
    }
  }
}

// --- 3) blocks <NG: per-chunk sums + atomic superchunk sums.
//        blocks >=NG (16): per-patient binary searches -> kk[b].
__global__ __launch_bounds__(256) void k_chunk(
    const float* __restrict__ eA, const float* __restrict__ eC,
    const int* __restrict__ idxs, const float* __restrict__ V,
    const float* __restrict__ s, const float* __restrict__ tsort,
    float* __restrict__ SA, float* __restrict__ SC,
    float* __restrict__ sa0, float* __restrict__ sc0,
    float* __restrict__ SSA, float* __restrict__ SSC,
    float* __restrict__ ssa0, float* __restrict__ ssc0,
    int* __restrict__ kk) {
  int g = blockIdx.x, d = threadIdx.x;
  if (g < NG) {
    int base = g * CS;
    float accA = 0.f, accC = 0.f, sa = 0.f, sc = 0.f;
    #pragma unroll
    for (int j = 0; j < CS; ++j) {
      int i = base + j;
      float ea = eA[i], ec = eC[i];
      float v = V[(size_t)idxs[i] * ND + d];
      accA += ea * v; accC += ec * v;
      sa += ea; sc += ec;
    }
    SA[(size_t)g * ND + d] = accA;
    SC[(size_t)g * ND + d] = accC;
    int gs = g / SCHUNK;
    atomicAdd(&SSA[(size_t)gs * ND + d], accA);
    atomicAdd(&SSC[(size_t)gs * ND + d], accC);
    if (d == 0) {
      sa0[g] = sa; sc0[g] = sc;
      atomicAdd(&ssa0[gs], sa);
      atomicAdd(&ssc0[gs], sc);
    }
  } else {
    int b = (g - NG) * 256 + d;           // 16 blocks x 256 = 4096 = NB
    if (b < NB) {
      float key = -s[b];
      int lo = 0, hi = NN;  // lower_bound: first idx with tsort[idx] >= key
      while (lo < hi) {
        int mid = (lo + hi) >> 1;
        if (tsort[mid] < key) lo = mid + 1; else hi = mid;
      }
      kk[b] = lo;
    }
  }
}

// --- 4) finalize: 512 blocks x 8 patients. Superchunk A/C prefixes built
// ONCE per block into LDS (53 KB); per patient: 2 LDS rows + <=24 chunk rows
// + <=15 V rows, fused epilogue.
__global__ __launch_bounds__(256) void k_finalize(
    const float* __restrict__ P, const float* __restrict__ V,
    const float* __restrict__ s, const int* __restrict__ kk,
    const float* __restrict__ eA, const float* __restrict__ eC,
    const int* __restrict__ idxs,
    const float* __restrict__ SA, const float* __restrict__ SC,
    const float* __restrict__ sa0, const float* __restrict__ sc0,
    const float* __restrict__ SSA, const float* __restrict__ SSC,
    const float* __restrict__ ssa0, const float* __restrict__ ssc0,
    float* __restrict__ out) {
  __shared__ float lpsa[(NSUPER + 1) * ND];   // exclusive prefix of SSA rows
  __shared__ float lpsc[(NSUPER + 1) * ND];   // exclusive prefix of SSC rows
  __shared__ float lpa0[NSUPER + 1], lpc0[NSUPER + 1];
  int d = threadIdx.x;
  float runA = 0.f, runC = 0.f;
  lpsa[d] = 0.f; lpsc[d] = 0.f;
  for (int q = 0; q < NSUPER; ++q) {
    runA += SSA[(size_t)q * ND + d];
    runC += SSC[(size_t)q * ND + d];
    lpsa[(q + 1) * ND + d] = runA;
    lpsc[(q + 1) * ND + d] = runC;
  }
  if (d == 0) {
    float ra = 0.f, rc = 0.f;
    lpa0[0] = 0.f; lpc0[0] = 0.f;
    for (int q = 0; q < NSUPER; ++q) {
      ra += ssa0[q]; rc += ssc0[q];
      lpa0[q + 1] = ra; lpc0[q + 1] = rc;
    }
  }
  __syncthreads();
  #pragma unroll 1
  for (int p = 0; p < FPB; ++p) {
    int b = blockIdx.x * FPB + p;
    int k = kk[b];
    int g = k >> 4;          // chunk idx; k==NN -> g==NG
    int gs = g / SCHUNK;     // superchunk idx; g==NG -> gs==NSUPER
    float suffA = lpsa[NSUPER * ND + d] - lpsa[gs * ND + d];
    float prefC = lpsc[gs * ND + d];
    float suffa = lpa0[NSUPER] - lpa0[gs];
    float prefc = lpc0[gs];
    for (int j = gs * SCHUNK; j < g; ++j) {
      suffA -= SA[(size_t)j * ND + d];
      prefC += SC[(size_t)j * ND + d];
      suffa -= sa0[j]; prefc += sc0[j];
    }
    for (int i = g << 4; i < k; ++i) {
      float ea = eA[i], ec = eC[i];
      float v = V[(size_t)idxs[i] * ND + d];
      suffA -= ea * v; prefC += ec * v;
      suffa -= ea; prefc += ec;
    }
    float sb = s[b];
    float ea = __expf(sb), ec = __expf(ALPHA * sb);
    float inv = 1.f / (ea * suffa + ec * prefc);
    out[(size_t)b * ND + d] = P[(size_t)b * ND + d] +
                              (ea * suffA + ec * prefC) * inv;
  }
}

extern "C" void kernel_launch(void* const* d_in, const int* in_sizes, int n_in,
                              void* d_out, int out_size, void* d_ws, size_t ws_size,
                              hipStream_t stream) {
  const float* P = (const float*)d_in[0];   // (B, D)
  const float* V = (const float*)d_in[1];   // (N, D)
  const float* K = (const float*)d_in[2];   // (2D, 1)
  float* out = (float*)d_out;

  char* w = (char*)d_ws;
  u64*   tk    = (u64*)w;   w += sizeof(u64) * NN;        // 8B-aligned first
  // --- zeroed-by-k_dot region (contiguous) ---
  int*   zreg  = (int*)w;
  int*   rank  = (int*)w;   w += sizeof(int) * NN;
  int*   ntdone= (int*)w;   w += sizeof(int) * NTILES;
  float* SSA   = (float*)w; w += sizeof(float) * NSUPER * ND;
  float* SSC   = (float*)w; w += sizeof(float) * NSUPER * ND;
  float* ssa0  = (float*)w; w += sizeof(float) * NSUPER;
  float* ssc0  = (float*)w; w += sizeof(float) * NSUPER;
  // --- rest ---
  float* t     = (float*)w; w += sizeof(float) * NN;
  float* s     = (float*)w; w += sizeof(float) * NB;
  float* tsort = (float*)w; w += sizeof(float) * NN;
  float* eA    = (float*)w; w += sizeof(float) * NN;
  float* eC    = (float*)w; w += sizeof(float) * NN;
  int*   idxs  = (int*)w;   w += sizeof(int) * NN;
  int*   kk    = (int*)w;   w += sizeof(int) * NB;
  float* SA    = (float*)w; w += sizeof(float) * (size_t)NG * ND;
  float* SC    = (float*)w; w += sizeof(float) * (size_t)NG * ND;
  float* sa0   = (float*)w; w += sizeof(float) * NG;
  float* sc0   = (float*)w; w += sizeof(float) * NG;

  k_dot<<<(NN + NB + 3) / 4, 256, 0, stream>>>(P, V, K, t, s, tk, zreg);
  k_rank_scatter<<<dim3(NTILES, MSEGS), 256, 0, stream>>>(
      tk, t, rank, ntdone, tsort, eA, eC, idxs);
  k_chunk<<<NG + NB / 256, 256, 0, stream>>>(
      eA, eC, idxs, V, s, tsort, SA, SC, sa0, sc0, SSA, SSC, ssa0, ssc0, kk);
  k_finalize<<<NB / FPB, 256, 0, stream>>>(
      P, V, s, kk, eA, eC, idxs, SA, SC, sa0, sc0, SSA, SSC, ssa0, ssc0, out);
}

// Round 9
// 139.706 us; speedup vs baseline: 1.6807x; 1.0428x over previous
//
#include <hip/hip_runtime.h>
#include <math.h>

#define NB 4096
#define NN 10000
#define ND 256
#define ALPHA 0.2f
#define CS 16                 // rows per chunk
#define NG (NN / CS)          // 625 chunks (exact)
#define SCHUNK 25             // chunks per superchunk
#define NSUPER (NG / SCHUNK)  // 25 superchunks (exact)
#define NTILES 40             // 40*256 >= 10000
#define MSEGS 26
#define SEGLEN ((NN + MSEGS - 1) / MSEGS)   // 385
// zero region: rank[NN] + ntdone[NTILES] + SSA/SSC + ssa0/ssc0
#define ZELEMS (NN + NTILES + 2 * NSUPER * ND + 2 * NSUPER)

typedef unsigned long long u64;

// --- 1) dots t_n=V[n]·Wn, s_b=P[b]·Wp (one wave/row); strict-total-order u64
// keys tk[n]; zero the atomic-accumulator region.  [identical to R5]
__global__ __launch_bounds__(256) void k_dot(
    const float* __restrict__ P, const float* __restrict__ V,
    const float* __restrict__ K,
    float* __restrict__ t, float* __restrict__ s, u64* __restrict__ tk,
    int* __restrict__ zero_region) {
  int gt = blockIdx.x * 256 + threadIdx.x;
  if (gt < ZELEMS) zero_region[gt] = 0;
  int j = blockIdx.x * 4 + (threadIdx.x >> 6);
  int lane = threadIdx.x & 63;
  if (j >= NN + NB) return;
  const float* row; const float* wv; int oi; bool isn;
  if (j < NN) { row = V + (size_t)j * ND; wv = K + ND; oi = j; isn = true; }
  else        { row = P + (size_t)(j - NN) * ND; wv = K; oi = j - NN; isn = false; }
  float4 r  = ((const float4*)row)[lane];
  float4 kx = ((const float4*)wv)[lane];
  float acc = r.x * kx.x + r.y * kx.y + r.z * kx.z + r.w * kx.w;
  #pragma unroll
  for (int off = 32; off; off >>= 1) acc += __shfl_down(acc, off, 64);
  if (lane == 0) {
    if (isn) {
      t[oi] = acc;
      unsigned bits = __float_as_uint(acc);
      unsigned key = bits ^ (((int)bits >> 31) | 0x80000000u);  // monotone map
      tk[oi] = ((u64)key << 14) | (unsigned)oi;
    } else {
      s[oi] = acc;
    }
  }
}

// --- 2) rank + winner-block scatter (THE ONLY CHANGE vs R5). Grid
// (NTILES, MSEGS). Partial ranks via wave-uniform key loads -> atomicAdd.
// ACQ_REL inc of ntdone[ntile]; the 26th arriver (its acquire synchronizes
// with the other 25 blocks' releases) issues one agent acquire fence, then
// scatters with plain coalesced loads of the final ranks.
__global__ __launch_bounds__(256) void k_rank_scatter(
    const u64* __restrict__ tk, const float* __restrict__ t,
    int* __restrict__ rank, int* __restrict__ ntdone,
    float* __restrict__ tsort, float* __restrict__ eA, float* __restrict__ eC,
    int* __restrict__ idxs) {
  int ntile = blockIdx.x, seg = blockIdx.y;
  int n = ntile * 256 + threadIdx.x;
  u64 kn = (n < NN) ? tk[n] : ~0ull;
  int m0 = seg * SEGLEN, m1 = min(NN, m0 + SEGLEN);
  int r = 0;
  int m = m0;
  #pragma unroll 1
  for (; m + 4 <= m1; m += 4) {
    u64 a = tk[m], b2 = tk[m + 1], c2 = tk[m + 2], d2 = tk[m + 3];
    r += (int)(a < kn) + (int)(b2 < kn) + (int)(c2 < kn) + (int)(d2 < kn);
  }
  for (; m < m1; ++m) r += (int)(tk[m] < kn);
  if (n < NN && r) atomicAdd(&rank[n], r);
  __syncthreads();
  __shared__ int who;
  if (threadIdx.x == 0)
    who = __hip_atomic_fetch_add(&ntdone[ntile], 1, __ATOMIC_ACQ_REL,
                                 __HIP_MEMORY_SCOPE_AGENT);
  __syncthreads();
  if (who == MSEGS - 1) {
    __builtin_amdgcn_fence(__ATOMIC_ACQUIRE, "agent");
    if (n < NN) {
      int rr = rank[n];
      float tn = t[n];
      tsort[rr] = tn;
      eA[rr] = __expf(tn);
      eC[rr] = __expf(ALPHA * tn);
      idxs[rr] = n;
    }
  }
}

// --- 3) blocks <NG: per-chunk sums + atomic superchunk sums.
//        blocks >=NG (16): per-patient binary searches.  [identical to R5]
__global__ __launch_bounds__(256) void k_chunk(
    const float* __restrict__ eA, const float* __restrict__ eC,
    const int* __restrict__ idxs, const float* __restrict__ V,
    const float* __restrict__ s, const float* __restrict__ tsort,
    float* __restrict__ SA, float* __restrict__ SC,
    float* __restrict__ sa0, float* __restrict__ sc0,
    float* __restrict__ SSA, float* __restrict__ SSC,
    float* __restrict__ ssa0, float* __restrict__ ssc0,
    int* __restrict__ kk) {
  int g = blockIdx.x, d = threadIdx.x;
  if (g < NG) {
    int base = g * CS;
    float accA = 0.f, accC = 0.f, sa = 0.f, sc = 0.f;
    #pragma unroll
    for (int j = 0; j < CS; ++j) {
      int i = base + j;
      float ea = eA[i], ec = eC[i];
      float v = V[(size_t)idxs[i] * ND + d];
      accA += ea * v; accC += ec * v;
      sa += ea; sc += ec;
    }
    SA[(size_t)g * ND + d] = accA;
    SC[(size_t)g * ND + d] = accC;
    int gs = g / SCHUNK;
    atomicAdd(&SSA[(size_t)gs * ND + d], accA);
    atomicAdd(&SSC[(size_t)gs * ND + d], accC);
    if (d == 0) {
      sa0[g] = sa; sc0[g] = sc;
      atomicAdd(&ssa0[gs], sa);
      atomicAdd(&ssc0[gs], sc);
    }
  } else {
    int b = (g - NG) * 256 + d;           // 16 blocks x 256 = 4096 = NB
    float key = -s[b];
    int lo = 0, hi = NN;  // lower_bound: first idx with tsort[idx] >= key
    while (lo < hi) {
      int mid = (lo + hi) >> 1;
      if (tsort[mid] < key) lo = mid + 1; else hi = mid;
    }
    kk[b] = lo;
  }
}

// --- 4) finalize: A-side as suffix sums, C-side as prefix sums (25 SS rows
// + <=24 chunk rows + <=15 V rows per block), fused epilogue. [identical to R5]
__global__ __launch_bounds__(256) void k_finalize(
    const float* __restrict__ P, const float* __restrict__ V,
    const float* __restrict__ s, const int* __restrict__ kk,
    const float* __restrict__ eA, const float* __restrict__ eC,
    const int* __restrict__ idxs,
    const float* __restrict__ SA, const float* __restrict__ SC,
    const float* __restrict__ sa0, const float* __restrict__ sc0,
    const float* __restrict__ SSA, const float* __restrict__ SSC,
    const float* __restrict__ ssa0, const float* __restrict__ ssc0,
    float* __restrict__ out) {
  int b = blockIdx.x, d = threadIdx.x;
  int k = kk[b];
  int g = k >> 4;          // chunk idx; k==NN -> g==NG
  int gs = g / SCHUNK;     // superchunk idx; g==NG -> gs==NSUPER
  float suffA = 0.f, prefC = 0.f, suffa = 0.f, prefc = 0.f;
  for (int q = gs; q < NSUPER; ++q) {
    suffA += SSA[(size_t)q * ND + d];
    suffa += ssa0[q];
  }
  for (int q = 0; q < gs; ++q) {
    prefC += SSC[(size_t)q * ND + d];
    prefc += ssc0[q];
  }
  for (int j = gs * SCHUNK; j < g; ++j) {
    suffA -= SA[(size_t)j * ND + d];
    prefC += SC[(size_t)j * ND + d];
    suffa -= sa0[j];
    prefc += sc0[j];
  }
  for (int i = g << 4; i < k; ++i) {
    float ea = eA[i], ec = eC[i];
    float v = V[(size_t)idxs[i] * ND + d];
    suffA -= ea * v; prefC += ec * v;
    suffa -= ea;     prefc += ec;
  }
  float sb = s[b];
  float ea = __expf(sb), ec = __expf(ALPHA * sb);
  float l = ea * suffa + ec * prefc;
  float agg = (ea * suffA + ec * prefC) / l;
  out[(size_t)b * ND + d] = P[(size_t)b * ND + d] + agg;
}

extern "C" void kernel_launch(void* const* d_in, const int* in_sizes, int n_in,
                              void* d_out, int out_size, void* d_ws, size_t ws_size,
                              hipStream_t stream) {
  const float* P = (const float*)d_in[0];   // (B, D)
  const float* V = (const float*)d_in[1];   // (N, D)
  const float* K = (const float*)d_in[2];   // (2D, 1)
  float* out = (float*)d_out;

  char* w = (char*)d_ws;
  u64*   tk    = (u64*)w;   w += sizeof(u64) * NN;        // 8B-aligned first
  // --- zeroed-by-k_dot region (contiguous) ---
  int*   zreg  = (int*)w;
  int*   rank  = (int*)w;   w += sizeof(int) * NN;
  int*   ntdone= (int*)w;   w += sizeof(int) * NTILES;
  float* SSA   = (float*)w; w += sizeof(float) * NSUPER * ND;
  float* SSC   = (float*)w; w += sizeof(float) * NSUPER * ND;
  float* ssa0  = (float*)w; w += sizeof(float) * NSUPER;
  float* ssc0  = (float*)w; w += sizeof(float) * NSUPER;
  // --- rest ---
  float* t     = (float*)w; w += sizeof(float) * NN;
  float* s     = (float*)w; w += sizeof(float) * NB;
  float* tsort = (float*)w; w += sizeof(float) * NN;
  float* eA    = (float*)w; w += sizeof(float) * NN;
  float* eC    = (float*)w; w += sizeof(float) * NN;
  int*   idxs  = (int*)w;   w += sizeof(int) * NN;
  int*   kk    = (int*)w;   w += sizeof(int) * NB;
  float* SA    = (float*)w; w += sizeof(float) * (size_t)NG * ND;
  float* SC    = (float*)w; w += sizeof(float) * (size_t)NG * ND;
  float* sa0   = (float*)w; w += sizeof(float) * NG;
  float* sc0   = (float*)w; w += sizeof(float) * NG;

  k_dot<<<(NN + NB + 3) / 4, 256, 0, stream>>>(P, V, K, t, s, tk, zreg);
  k_rank_scatter<<<dim3(NTILES, MSEGS), 256, 0, stream>>>(
      tk, t, rank, ntdone, tsort, eA, eC, idxs);
  k_chunk<<<NG + NB / 256, 256, 0, stream>>>(
      eA, eC, idxs, V, s, tsort, SA, SC, sa0, sc0, SSA, SSC, ssa0, ssc0, kk);
  k_finalize<<<NB, 256, 0, stream>>>(
      P, V, s, kk, eA, eC, idxs, SA, SC, sa0, sc0, SSA, SSC, ssa0, ssc0, out);
}

// Round 10
// 134.122 us; speedup vs baseline: 1.7507x; 1.0416x over previous
//
#include <hip/hip_runtime.h>
#include <math.h>

#define NB 4096
#define NN 10000
#define ND 256
#define ALPHA 0.2f
#define CS 16                 // rows per chunk
#define NG (NN / CS)          // 625 chunks (exact)
#define SCHUNK 25             // chunks per superchunk
#define NSUPER (NG / SCHUNK)  // 25 superchunks (exact)
#define MSEGS 26
#define SEGLEN ((NN + MSEGS - 1) / MSEGS)   // 385
#define FPB 4                 // patients per finalize block
// zero region: rank[NN] + SSA/SSC + ssa0/ssc0
#define ZELEMS (NN + 2 * NSUPER * ND + 2 * NSUPER)

typedef unsigned long long u64;

// --- 1) dots t_n=V[n]·Wn, s_b=P[b]·Wp (one wave/row); strict-total-order u64
// keys tk[n]; zero the atomic-accumulator region.  [identical to R5]
__global__ __launch_bounds__(256) void k_dot(
    const float* __restrict__ P, const float* __restrict__ V,
    const float* __restrict__ K,
    float* __restrict__ t, float* __restrict__ s, u64* __restrict__ tk,
    int* __restrict__ zero_region) {
  int gt = blockIdx.x * 256 + threadIdx.x;
  if (gt < ZELEMS) zero_region[gt] = 0;
  int j = blockIdx.x * 4 + (threadIdx.x >> 6);
  int lane = threadIdx.x & 63;
  if (j >= NN + NB) return;
  const float* row; const float* wv; int oi; bool isn;
  if (j < NN) { row = V + (size_t)j * ND; wv = K + ND; oi = j; isn = true; }
  else        { row = P + (size_t)(j - NN) * ND; wv = K; oi = j - NN; isn = false; }
  float4 r  = ((const float4*)row)[lane];
  float4 kx = ((const float4*)wv)[lane];
  float acc = r.x * kx.x + r.y * kx.y + r.z * kx.z + r.w * kx.w;
  #pragma unroll
  for (int off = 32; off; off >>= 1) acc += __shfl_down(acc, off, 64);
  if (lane == 0) {
    if (isn) {
      t[oi] = acc;
      unsigned bits = __float_as_uint(acc);
      unsigned key = bits ^ (((int)bits >> 31) | 0x80000000u);  // monotone map
      tk[oi] = ((u64)key << 14) | (unsigned)oi;
    } else {
      s[oi] = acc;
    }
  }
}

// --- 2) rank[n] = #{m : tk[m] < tk[n]} via wave-uniform key loads.
// [identical to R5 — standalone, no fusion: measured cheapest]
__global__ __launch_bounds__(256) void k_rank(
    const u64* __restrict__ tk, int* __restrict__ rank) {
  int n = blockIdx.x * 256 + threadIdx.x;
  u64 kn = (n < NN) ? tk[n] : ~0ull;
  int m0 = blockIdx.y * SEGLEN;
  int m1 = min(NN, m0 + SEGLEN);
  int r = 0;
  int m = m0;
  #pragma unroll 1
  for (; m + 4 <= m1; m += 4) {
    u64 a = tk[m], b2 = tk[m + 1], c2 = tk[m + 2], d2 = tk[m + 3];
    r += (int)(a < kn) + (int)(b2 < kn) + (int)(c2 < kn) + (int)(d2 < kn);
  }
  for (; m < m1; ++m) r += (int)(tk[m] < kn);
  if (n < NN && r) atomicAdd(&rank[n], r);
}

// --- 3) scatter into sorted order + exp factors.  [identical to R5]
__global__ __launch_bounds__(256) void k_scatter(
    const float* __restrict__ t, const int* __restrict__ rank,
    float* __restrict__ tsort, float* __restrict__ eA, float* __restrict__ eC,
    int* __restrict__ idxs) {
  int n = blockIdx.x * 256 + threadIdx.x;
  if (n < NN) {
    int r = rank[n];
    float tn = t[n];
    tsort[r] = tn;
    eA[r] = __expf(tn);
    eC[r] = __expf(ALPHA * tn);
    idxs[r] = n;
  }
}

// --- 4) blocks <NG: per-chunk sums + atomic superchunk sums.
//        blocks >=NG (16): per-patient binary searches.  [identical to R5]
__global__ __launch_bounds__(256) void k_chunk(
    const float* __restrict__ eA, const float* __restrict__ eC,
    const int* __restrict__ idxs, const float* __restrict__ V,
    const float* __restrict__ s, const float* __restrict__ tsort,
    float* __restrict__ SA, float* __restrict__ SC,
    float* __restrict__ sa0, float* __restrict__ sc0,
    float* __restrict__ SSA, float* __restrict__ SSC,
    float* __restrict__ ssa0, float* __restrict__ ssc0,
    int* __restrict__ kk) {
  int g = blockIdx.x, d = threadIdx.x;
  if (g < NG) {
    int base = g * CS;
    float accA = 0.f, accC = 0.f, sa = 0.f, sc = 0.f;
    #pragma unroll
    for (int j = 0; j < CS; ++j) {
      int i = base + j;
      float ea = eA[i], ec = eC[i];
      float v = V[(size_t)idxs[i] * ND + d];
      accA += ea * v; accC += ec * v;
      sa += ea; sc += ec;
    }
    SA[(size_t)g * ND + d] = accA;
    SC[(size_t)g * ND + d] = accC;
    int gs = g / SCHUNK;
    atomicAdd(&SSA[(size_t)gs * ND + d], accA);
    atomicAdd(&SSC[(size_t)gs * ND + d], accC);
    if (d == 0) {
      sa0[g] = sa; sc0[g] = sc;
      atomicAdd(&ssa0[gs], sa);
      atomicAdd(&ssc0[gs], sc);
    }
  } else {
    int b = (g - NG) * 256 + d;           // 16 blocks x 256 = 4096 = NB
    float key = -s[b];
    int lo = 0, hi = NN;  // lower_bound: first idx with tsort[idx] >= key
    while (lo < hi) {
      int mid = (lo + hi) >> 1;
      if (tsort[mid] < key) lo = mid + 1; else hi = mid;
    }
    kk[b] = lo;
  }
}

// --- 5) finalize (THE ONLY CHANGE vs R5): 4 patients per block. Superchunk
// rows loaded once and predicated into the 4 patients' suffix(A)/prefix(C)
// accumulators (12.5 rows/patient vs 25); chunk rows + V remainder per
// patient; fused epilogue. No LDS, no fences.
__global__ __launch_bounds__(256) void k_finalize(
    const float* __restrict__ P, const float* __restrict__ V,
    const float* __restrict__ s, const int* __restrict__ kk,
    const float* __restrict__ eA, const float* __restrict__ eC,
    const int* __restrict__ idxs,
    const float* __restrict__ SA, const float* __restrict__ SC,
    const float* __restrict__ sa0, const float* __restrict__ sc0,
    const float* __restrict__ SSA, const float* __restrict__ SSC,
    const float* __restrict__ ssa0, const float* __restrict__ ssc0,
    float* __restrict__ out) {
  int d = threadIdx.x;
  int b0 = blockIdx.x * FPB;
  int kq[FPB], gq[FPB], gsq[FPB];
  float suffA[FPB], prefC[FPB], suffa[FPB], prefc[FPB];
  #pragma unroll
  for (int p = 0; p < FPB; ++p) {
    kq[p] = kk[b0 + p];
    gq[p] = kq[p] >> 4;          // chunk idx; k==NN -> g==NG
    gsq[p] = gq[p] / SCHUNK;     // superchunk idx; g==NG -> gs==NSUPER
    suffA[p] = 0.f; prefC[p] = 0.f; suffa[p] = 0.f; prefc[p] = 0.f;
  }
  // shared superchunk-row pass (q ascending; per-patient order same as R5)
  for (int q = 0; q < NSUPER; ++q) {
    float vA = SSA[(size_t)q * ND + d];
    float vC = SSC[(size_t)q * ND + d];
    float a0 = ssa0[q], c0 = ssc0[q];
    #pragma unroll
    for (int p = 0; p < FPB; ++p) {
      if (q >= gsq[p]) { suffA[p] += vA; suffa[p] += a0; }
      else             { prefC[p] += vC; prefc[p] += c0; }
    }
  }
  // per-patient chunk rows + element remainder + epilogue
  #pragma unroll
  for (int p = 0; p < FPB; ++p) {
    int g = gq[p], gs = gsq[p], k = kq[p];
    for (int j = gs * SCHUNK; j < g; ++j) {
      suffA[p] -= SA[(size_t)j * ND + d];
      prefC[p] += SC[(size_t)j * ND + d];
      suffa[p] -= sa0[j];
      prefc[p] += sc0[j];
    }
    for (int i = g << 4; i < k; ++i) {
      float ea = eA[i], ec = eC[i];
      float v = V[(size_t)idxs[i] * ND + d];
      suffA[p] -= ea * v; prefC[p] += ec * v;
      suffa[p] -= ea;     prefc[p] += ec;
    }
    float sb = s[b0 + p];
    float ea = __expf(sb), ec = __expf(ALPHA * sb);
    float l = ea * suffa[p] + ec * prefc[p];
    out[(size_t)(b0 + p) * ND + d] =
        P[(size_t)(b0 + p) * ND + d] + (ea * suffA[p] + ec * prefC[p]) / l;
  }
}

extern "C" void kernel_launch(void* const* d_in, const int* in_sizes, int n_in,
                              void* d_out, int out_size, void* d_ws, size_t ws_size,
                              hipStream_t stream) {
  const float* P = (const float*)d_in[0];   // (B, D)
  const float* V = (const float*)d_in[1];   // (N, D)
  const float* K = (const float*)d_in[2];   // (2D, 1)
  float* out = (float*)d_out;

  char* w = (char*)d_ws;
  u64*   tk    = (u64*)w;   w += sizeof(u64) * NN;        // 8B-aligned first
  // --- zeroed-by-k_dot region (contiguous) ---
  int*   zreg  = (int*)w;
  int*   rank  = (int*)w;   w += sizeof(int) * NN;
  float* SSA   = (float*)w; w += sizeof(float) * NSUPER * ND;
  float* SSC   = (float*)w; w += sizeof(float) * NSUPER * ND;
  float* ssa0  = (float*)w; w += sizeof(float) * NSUPER;
  float* ssc0  = (float*)w; w += sizeof(float) * NSUPER;
  // --- rest ---
  float* t     = (float*)w; w += sizeof(float) * NN;
  float* s     = (float*)w; w += sizeof(float) * NB;
  float* tsort = (float*)w; w += sizeof(float) * NN;
  float* eA    = (float*)w; w += sizeof(float) * NN;
  float* eC    = (float*)w; w += sizeof(float) * NN;
  int*   idxs  = (int*)w;   w += sizeof(int) * NN;
  int*   kk    = (int*)w;   w += sizeof(int) * NB;
  float* SA    = (float*)w; w += sizeof(float) * (size_t)NG * ND;
  float* SC    = (float*)w; w += sizeof(float) * (size_t)NG * ND;
  float* sa0   = (float*)w; w += sizeof(float) * NG;
  float* sc0   = (float*)w; w += sizeof(float) * NG;

  k_dot<<<(NN + NB + 3) / 4, 256, 0, stream>>>(P, V, K, t, s, tk, zreg);
  k_rank<<<dim3((NN + 255) / 256, MSEGS), 256, 0, stream>>>(tk, rank);
  k_scatter<<<(NN + 255) / 256, 256, 0, stream>>>(t, rank, tsort, eA, eC, idxs);
  k_chunk<<<NG + NB / 256, 256, 0, stream>>>(
      eA, eC, idxs, V, s, tsort, SA, SC, sa0, sc0, SSA, SSC, ssa0, ssc0, kk);
  k_finalize<<<NB / FPB, 256, 0, stream>>>(
      P, V, s, kk, eA, eC, idxs, SA, SC, sa0, sc0, SSA, SSC, ssa0, ssc0, out);
}